// Round 8
// baseline (221.499 us; speedup 1.0000x reference)
//
#include <hip/hip_runtime.h>

#define NT      2000
#define BATCH   4096
#define NODES   64
#define TBL_N   8192
#define JMAX    3.6f
#define TBLOCKS (TBL_N / 256)

// ---------------- MLP evaluation helper (build phase only) ----------------
__device__ __forceinline__ float mlp_rho(float j,
    const float* sW1, const float* sB1, const float* sW2,
    const float* sB2, const float* sW3, float b3v) {
    float h1[NODES];
#pragma unroll
    for (int k = 0; k < NODES; ++k)
        h1[k] = fmaxf(fmaf(j, sW1[k], sB1[k]), 0.0f);
    float rho = b3v;
    for (int nt = 0; nt < NODES; nt += 8) {
        float acc[8];
#pragma unroll
        for (int q = 0; q < 8; ++q) acc[q] = sB2[nt + q];
#pragma unroll
        for (int k = 0; k < NODES; ++k) {
            float a = h1[k];
#pragma unroll
            for (int q = 0; q < 8; ++q)
                acc[q] = fmaf(a, sW2[k * NODES + nt + q], acc[q]);
        }
#pragma unroll
        for (int q = 0; q < 8; ++q)
            rho = fmaf(fmaxf(acc[q], 0.0f), sW3[nt + q], rho);
    }
    return rho;
}

// ------ kernel 1: blocks [0,32) build rho table; rest fill time plane ------
__global__ __launch_bounds__(256) void prep(
    const float* __restrict__ W1, const float* __restrict__ b1,
    const float* __restrict__ W2, const float* __restrict__ b2,
    const float* __restrict__ W3, const float* __restrict__ b3,
    float2* __restrict__ tbl, float* __restrict__ out) {
    __shared__ float sW2[NODES * NODES];
    __shared__ float sW1[NODES], sB1[NODES], sB2[NODES], sW3[NODES];
    __shared__ float sB3;

    if (blockIdx.x < TBLOCKS) {
        for (int i = threadIdx.x; i < NODES * NODES; i += 256) sW2[i] = W2[i];
        if (threadIdx.x < NODES) {
            sW1[threadIdx.x] = W1[threadIdx.x];
            sB1[threadIdx.x] = b1[threadIdx.x];
            sB2[threadIdx.x] = b2[threadIdx.x];
            sW3[threadIdx.x] = W3[threadIdx.x];
        }
        if (threadIdx.x == 0) sB3 = b3[0];
        __syncthreads();

        int idx = blockIdx.x * 256 + threadIdx.x;
        const float h = JMAX / (float)TBL_N;
        float j0 = h * (float)idx;
        float v0 = mlp_rho(j0,     sW1, sB1, sW2, sB2, sW3, sB3);
        float v1 = mlp_rho(j0 + h, sW1, sB1, sW2, sB2, sW3, sB3);
        tbl[idx] = make_float2(v0, v1 - v0);
    } else {
        int e = (blockIdx.x - TBLOCKS) * 256 + threadIdx.x;   // float4 index
        int t0 = (e * 4) % NT;                                // NT % 4 == 0
        float4 v = make_float4(0.1f * (float)t0, 0.1f * (float)(t0 + 1),
                               0.1f * (float)(t0 + 2), 0.1f * (float)(t0 + 3));
        reinterpret_cast<float4*>(out + 3 * (size_t)BATCH * NT)[e] = v;
    }
}

// 8-step block: prefetch rho pairs for OB+8..OB+15 into bank B (consumed
// next block, ~1 block of slack over LDS latency), run 8 recurrence steps
// consuming bank A, emit two packed float4 stores.
#define BLOCK8(AV, AD, AF, BV, BD, BF, GATED, OB)                           \
  {                                                                         \
    _Pragma("unroll")                                                       \
    for (int t = 0; t < 8; ++t) {                                           \
      float p = fmaf((float)(t + 9), dxe, xe);                              \
      p = fminf(fmaxf(p, 0.0f), (float)(TBL_N - 2));                        \
      int ip = (int)p;                                                      \
      BF[t] = p - (float)ip;                                                \
      float2 vd = stbl[ip];                                                 \
      BV[t] = vd.x; BD[t] = vd.y;                                           \
    }                                                                       \
    float rq[8];                                                            \
    float jc6 = 0.0f, jc7 = 0.0f;                                           \
    _Pragma("unroll")                                                       \
    for (int t = 0; t < 8; ++t) {                                           \
      const int o = (OB) + t;                                               \
      float rho = fmaf(AF[t], AD[t], AV[t]);       /* off-chain */          \
      float at  = rho * k1;                        /* off-chain */          \
      float bt  = at * njm;                        /* off-chain */          \
      float co  = 0.014f * (float)o;               /* wave-uniform */       \
      float jc  = co * w;                          /* chain */              \
      float u   = fmaf(at, jc, bt);                /* chain */              \
      float dn  = fmaxf(den + u, 8.0f);            /* chain */              \
      if (GATED) dn = (o >= nc) ? dn : den;        /* chain */              \
      float tc  = fmaf(-dn, w, 2.0f);              /* chain (Newton) */     \
      w   = w * tc;                                /* chain */              \
      den = dn;                                                             \
      rq[t] = fmaf(den, 7.14285714f, -7.14285714f); /* off-chain */         \
      if (t == 6) jc6 = jc;                                                 \
      if (t == 7) jc7 = jc;                                                 \
    }                                                                       \
    *reinterpret_cast<float4*>(oR + (OB)) =                                 \
        make_float4(rq[0], rq[1], rq[2], rq[3]);                            \
    *reinterpret_cast<float4*>(oR + (OB) + 4) =                             \
        make_float4(rq[4], rq[5], rq[6], rq[7]);                            \
    float x7 = jc7 * invh, x6 = jc6 * invh;                                 \
    dxe = x7 - x6; xe = x7;                                                 \
  }

// ---------------- kernel 2: sequential res recurrence only ----------------
__global__ __launch_bounds__(64, 1) void res_chain(
    const float* __restrict__ Cv, const float* __restrict__ K,
    const float* __restrict__ jmin, const float2* __restrict__ tbl,
    int* __restrict__ ncArr, float* __restrict__ out) {
    __shared__ float2 stbl[TBL_N];    // 64 KB
    const int l = threadIdx.x;
    for (int i = l; i < TBL_N / 2; i += 64)
        reinterpret_cast<float4*>(stbl)[i] =
            reinterpret_cast<const float4*>(tbl)[i];
    __syncthreads();

    const int b = blockIdx.x * 64 + l;
    const float cv = Cv[b];
    const float kk = K[b];
    const float jm = jmin[b];
    const float Qmin = 3.3068376f * powf(kk, 1.3333334f);
    const float k1   = 0.14f * cv * 0.1f;     // 0.14*cv*DT
    const float njm  = -jm;
    const float invh = (float)TBL_N / JMAX;

    float* __restrict__ oR = out + (size_t)BATCH * NT + (size_t)b * NT;

    // ---- Phase A: crossing step n_c (Q strictly increasing pre-cross) ----
    int nc = 1 << 20;
    {
        float Q = 0.0f;
        for (int o = 1; o <= 360; ++o) {
            float BC = 0.1f * (float)o;
            float jc = (0.14f * BC) * 0.125f;   // res == 50 exactly pre-cross
            Q = fmaf(jc, 0.1f, Q);
            if (Q > Qmin) { nc = o; break; }
        }
        nc = min(nc, NT - 1);
    }
    ncArr[b] = nc;
    int nmin = nc, nmax = nc;
#pragma unroll
    for (int m = 32; m >= 1; m >>= 1) {
        nmin = min(nmin, __shfl_xor(nmin, m, 64));
        nmax = max(nmax, __shfl_xor(nmax, m, 64));
    }
    const int G  = (NT - nmin + 7) >> 3;     // 8-step blocks
    const int o0 = NT - 8 * G;               // first simulated step (mult of 8)
    const int Gg = (nmax - o0 + 7) >> 3;     // blocks needing the gate

    // ---- fill res = 50 for o in [0, o0) ----
    for (int k = 0; k < (o0 >> 2); ++k)
        reinterpret_cast<float4*>(oR)[k] = make_float4(50.f, 50.f, 50.f, 50.f);

    // ---- pipelined sequential recurrence from o0 (den/w state) ----
    float den = 8.0f;        // 1 + 0.14*50
    float w   = 0.125f;      // 1/den, tracked by Newton

    float Av[8], Ad[8], Af[8], Bv[8], Bd[8], Bf[8];
#pragma unroll
    for (int t = 0; t < 8; ++t) {            // analytic prefill (res==50 here)
        float x = (0.00175f * (float)(o0 + t)) * invh;
        int ip = (int)x;
        Af[t] = x - (float)ip;
        float2 vd = stbl[ip];
        Av[t] = vd.x; Ad[t] = vd.y;
    }
    float xe  = (0.00175f * (float)(o0 - 1)) * invh;
    float dxe = 0.00175f * invh;             // exact pre-cross per-step delta

    int ob = o0;
    for (int i = 0; i < Gg; ++i) {
        BLOCK8(Av, Ad, Af, Bv, Bd, Bf, true, ob);
        ob += 8;
        // swap banks by alternating macro args on next iteration:
        if (++i >= Gg) { // keep parity handling simple: do B-block if room
            if (i <= Gg) {} // (fallthrough handled below)
        }
        --i; // restore (loop structure below handles parity explicitly)
        break;
    }
    // Explicit parity-managed loops (banks alternate A<->B every block):
    {
        int i = 0;
        bool useA = (o0 != ob);   // true if one gated block already ran
        if (useA) i = 1;
        for (; i < Gg; ++i) {
            if (((i ^ (useA ? 1 : 0)) & 1) == 0) {
                if (useA) { BLOCK8(Bv, Bd, Bf, Av, Ad, Af, true, ob); }
                else      { BLOCK8(Av, Ad, Af, Bv, Bd, Bf, true, ob); }
            } else {
                if (useA) { BLOCK8(Av, Ad, Af, Bv, Bd, Bf, true, ob); }
                else      { BLOCK8(Bv, Bd, Bf, Av, Ad, Af, true, ob); }
            }
            ob += 8;
        }
        for (int i2 = Gg; i2 < G; ++i2) {
            if (((ob - o0) >> 3) & 1) {
                BLOCK8(Bv, Bd, Bf, Av, Ad, Af, false, ob);
            } else {
                BLOCK8(Av, Ad, Af, Bv, Bd, Bf, false, ob);
            }
            ob += 8;
        }
    }
}

// ---------------- kernel 3: parallel expansion (j, thk) ----------------
__global__ __launch_bounds__(256) void expand(
    const float* __restrict__ Cv, const float* __restrict__ jmin,
    const int* __restrict__ ncArr, float* __restrict__ out) {
    const int lane = threadIdx.x & 63;
    const int b = blockIdx.x * 4 + (threadIdx.x >> 6);

    const float cv = Cv[b];
    const float jm = jmin[b];
    const float cvDT = cv * 0.1f;
    const int   nc = ncArr[b];

    const float* __restrict__ R = out + (size_t)BATCH * NT + (size_t)b * NT;
    float* __restrict__ T = out + (size_t)b * NT;
    float* __restrict__ C = out + 2 * (size_t)BATCH * NT + (size_t)b * NT;

    float y = 0.0f;
    float carry_res = 50.0f;

    for (int k = 0; k < (NT + 63) / 64; ++k) {
        const int o = 64 * k + lane;
        const int ol = min(o, NT - 1);
        float rv = R[ol];

        float resp = __shfl_up(rv, 1, 64);
        if (lane == 0) resp = carry_res;
        carry_res = __shfl(rv, 63, 64);

        float BC = 0.1f * (float)o;
        float j = (0.14f * BC) * __builtin_amdgcn_rcpf(fmaf(0.14f, resp, 1.0f));
        if (o == 0) j = 1e-3f;

        const bool active = (o >= nc);
        float S  = active ? cvDT * (j - jm) : 0.0f;
        float Cq = active ? 0.0f : -1e30f;

#pragma unroll
        for (int m = 1; m < 64; m <<= 1) {
            float Su = __shfl_up(S, m, 64);
            float Cu = __shfl_up(Cq, m, 64);
            if (lane >= m) {
                Cq = fmaxf(Cu + S, Cq);
                S  = Su + S;
            }
        }
        float thk = fmaxf(y + S, Cq);
        y = __shfl(thk, 63, 64);

        if (o < NT) {
            T[o] = thk;
            C[o] = j;
        }
    }
}

extern "C" void kernel_launch(void* const* d_in, const int* in_sizes, int n_in,
                              void* d_out, int out_size, void* d_ws, size_t ws_size,
                              hipStream_t stream) {
    const float* Cv   = (const float*)d_in[0];
    const float* K    = (const float*)d_in[1];
    const float* jmin = (const float*)d_in[2];
    const float* W1   = (const float*)d_in[3];
    const float* b1   = (const float*)d_in[4];
    const float* W2   = (const float*)d_in[5];
    const float* b2   = (const float*)d_in[6];
    const float* W3   = (const float*)d_in[7];
    const float* b3   = (const float*)d_in[8];
    float* out = (float*)d_out;
    float2* tbl  = (float2*)d_ws;                               // 64 KB
    int*    ncA  = (int*)((char*)d_ws + TBL_N * sizeof(float2)); // 16 KB

    const int fill_blocks = (BATCH * NT / 4) / 256;   // 8000
    prep<<<TBLOCKS + fill_blocks, 256, 0, stream>>>(W1, b1, W2, b2, W3, b3, tbl, out);
    res_chain<<<BATCH / 64, 64, 0, stream>>>(Cv, K, jmin, tbl, ncA, out);
    expand<<<BATCH / 4, 256, 0, stream>>>(Cv, jmin, ncA, out);
}

// Round 9
// 102.972 us; speedup vs baseline: 2.1511x; 2.1511x over previous
//
#include <hip/hip_runtime.h>

#define NT      2000
#define BATCH   4096
#define NODES   64
#define TBL_N   8192
#define JMAX    3.6f
#define TBLOCKS (TBL_N / 256)
#define FILLB   (BATCH * NT / 4 / 256)   // 8000 time-plane fill blocks
#define NCB     (BATCH / 256)            // 16 nc-compute blocks
#define MAXIT   24

// ---------------- MLP evaluation helper (build phase only) ----------------
__device__ __forceinline__ float mlp_rho(float j,
    const float* sW1, const float* sB1, const float* sW2,
    const float* sB2, const float* sW3, float b3v) {
    float h1[NODES];
#pragma unroll
    for (int k = 0; k < NODES; ++k)
        h1[k] = fmaxf(fmaf(j, sW1[k], sB1[k]), 0.0f);
    float rho = b3v;
    for (int nt = 0; nt < NODES; nt += 8) {
        float acc[8];
#pragma unroll
        for (int q = 0; q < 8; ++q) acc[q] = sB2[nt + q];
#pragma unroll
        for (int k = 0; k < NODES; ++k) {
            float a = h1[k];
#pragma unroll
            for (int q = 0; q < 8; ++q)
                acc[q] = fmaf(a, sW2[k * NODES + nt + q], acc[q]);
        }
#pragma unroll
        for (int q = 0; q < 8; ++q)
            rho = fmaf(fmaxf(acc[q], 0.0f), sW3[nt + q], rho);
    }
    return rho;
}

// kernel 1: [0,32) rho table · [32,8032) time plane · [8032,8048) nc per chain
__global__ __launch_bounds__(256) void prep(
    const float* __restrict__ W1, const float* __restrict__ b1,
    const float* __restrict__ W2, const float* __restrict__ b2,
    const float* __restrict__ W3, const float* __restrict__ b3,
    const float* __restrict__ K,
    float* __restrict__ tbl, int* __restrict__ ncArr,
    float* __restrict__ out) {
    if (blockIdx.x < TBLOCKS) {
        __shared__ float sW2[NODES * NODES];
        __shared__ float sW1[NODES], sB1[NODES], sB2[NODES], sW3[NODES];
        __shared__ float sB3;
        for (int i = threadIdx.x; i < NODES * NODES; i += 256) sW2[i] = W2[i];
        if (threadIdx.x < NODES) {
            sW1[threadIdx.x] = W1[threadIdx.x];
            sB1[threadIdx.x] = b1[threadIdx.x];
            sB2[threadIdx.x] = b2[threadIdx.x];
            sW3[threadIdx.x] = W3[threadIdx.x];
        }
        if (threadIdx.x == 0) sB3 = b3[0];
        __syncthreads();
        int idx = blockIdx.x * 256 + threadIdx.x;
        const float h = JMAX / (float)TBL_N;
        tbl[idx] = mlp_rho(h * (float)idx, sW1, sB1, sW2, sB2, sW3, sB3);
    } else if (blockIdx.x < TBLOCKS + FILLB) {
        int e = (blockIdx.x - TBLOCKS) * 256 + threadIdx.x;   // float4 index
        int t0 = (e * 4) % NT;                                // NT % 4 == 0
        float4 v = make_float4(0.1f * (float)t0, 0.1f * (float)(t0 + 1),
                               0.1f * (float)(t0 + 2), 0.1f * (float)(t0 + 3));
        reinterpret_cast<float4*>(out + 3 * (size_t)BATCH * NT)[e] = v;
    } else {
        int b = (blockIdx.x - TBLOCKS - FILLB) * 256 + threadIdx.x;
        float Qmin = 3.3068376f * powf(K[b], 1.3333334f);
        int nc = 1 << 20;
        float Q = 0.0f;
        for (int o = 1; o <= 360; ++o) {
            float BC = 0.1f * (float)o;
            float jc = (0.14f * BC) * 0.125f;   // res == 50 exactly pre-cross
            Q = fmaf(jc, 0.1f, Q);
            if (Q > Qmin) { nc = o; break; }
        }
        ncArr[b] = min(nc, NT - 1);
    }
}

// kernel 2: parallel-in-time res solve — one wave per chain, 64 steps/chunk,
// Jacobi/Picard iteration with clamped-prefix (S,C) scan per sweep.
__global__ __launch_bounds__(256) void res_solve(
    const float* __restrict__ Cv, const float* __restrict__ jmin,
    const int* __restrict__ ncArr, const float* __restrict__ tbl,
    float* __restrict__ out) {
    __shared__ float stbl[TBL_N];    // 32 KB
    for (int i = threadIdx.x; i < TBL_N / 4; i += 256)
        reinterpret_cast<float4*>(stbl)[i] =
            reinterpret_cast<const float4*>(tbl)[i];
    __syncthreads();

    const int lane = threadIdx.x & 63;
    const int b = blockIdx.x * 4 + (threadIdx.x >> 6);
    const float cv = Cv[b];
    const float jm = jmin[b];
    const int   nc = ncArr[b];
    const float k1 = cv * 0.1f;
    const float invh = (float)TBL_N / JMAX;
    float* __restrict__ oR = out + (size_t)BATCH * NT + (size_t)b * NT;

    const int o0 = nc & ~63;             // chunk-aligned start (nc >= ~122)
    for (int k4 = lane; k4 < (o0 >> 2); k4 += 64)
        reinterpret_cast<float4*>(oR)[k4] = make_float4(50.f, 50.f, 50.f, 50.f);

    const int NCH = (NT - o0 + 63) >> 6;
    float carry = 50.0f, slope = 0.0f;

    for (int c = 0; c < NCH; ++c) {
        const int o = o0 + (c << 6) + lane;
        const bool act = (o >= nc) && (o < NT);
        const float co = 0.14f * (0.1f * (float)o);   // match reference rounding
        float res_g = fmaf(slope, (float)(lane + 1), carry);

        for (int it = 0; it < MAXIT; ++it) {
            float resp = __shfl_up(res_g, 1, 64);
            if (lane == 0) resp = carry;
            float jc = co * __builtin_amdgcn_rcpf(fmaf(0.14f, resp, 1.0f));
            float x = fminf(fmaxf(jc * invh, 0.0f), (float)(TBL_N - 2));
            int ip = (int)x;
            float fr = x - (float)ip;
            float t0 = stbl[ip], t1 = stbl[ip + 1];
            float rho = fmaf(fr, t1 - t0, t0);
            float inc = rho * k1 * (jc - jm);

            float S = act ? inc : 0.0f;
            float C = act ? 50.0f : -3.0e38f;
#pragma unroll
            for (int m = 1; m < 64; m <<= 1) {
                float Su = __shfl_up(S, m, 64);
                float Cu = __shfl_up(C, m, 64);
                if (lane >= m) { C = fmaxf(Cu + S, C); S = Su + S; }
            }
            float rn = fmaxf(carry + S, C);
            float d = fabsf(rn - res_g);
            res_g = rn;
            if (__all(d <= 1.0e-3f)) break;
        }

        if (o < NT) oR[o] = res_g;       // coalesced (o0 multiple of 64)
        float last = __shfl(res_g, 63, 64);
        slope = (last - carry) * 0.015625f;
        carry = last;
    }
}

// kernel 3: parallel expansion (j, thk) — validated in rounds 7/8.
__global__ __launch_bounds__(256) void expand(
    const float* __restrict__ Cv, const float* __restrict__ jmin,
    const int* __restrict__ ncArr, float* __restrict__ out) {
    const int lane = threadIdx.x & 63;
    const int b = blockIdx.x * 4 + (threadIdx.x >> 6);

    const float cv = Cv[b];
    const float jm = jmin[b];
    const float cvDT = cv * 0.1f;
    const int   nc = ncArr[b];

    const float* __restrict__ R = out + (size_t)BATCH * NT + (size_t)b * NT;
    float* __restrict__ T = out + (size_t)b * NT;
    float* __restrict__ C = out + 2 * (size_t)BATCH * NT + (size_t)b * NT;

    float y = 0.0f;
    float carry_res = 50.0f;

    for (int k = 0; k < (NT + 63) / 64; ++k) {
        const int o = 64 * k + lane;
        const int ol = min(o, NT - 1);
        float rv = R[ol];

        float resp = __shfl_up(rv, 1, 64);
        if (lane == 0) resp = carry_res;
        carry_res = __shfl(rv, 63, 64);

        float BC = 0.1f * (float)o;
        float j = (0.14f * BC) * __builtin_amdgcn_rcpf(fmaf(0.14f, resp, 1.0f));
        if (o == 0) j = 1e-3f;

        const bool active = (o >= nc);
        float S  = active ? cvDT * (j - jm) : 0.0f;
        float Cq = active ? 0.0f : -1e30f;

#pragma unroll
        for (int m = 1; m < 64; m <<= 1) {
            float Su = __shfl_up(S, m, 64);
            float Cu = __shfl_up(Cq, m, 64);
            if (lane >= m) {
                Cq = fmaxf(Cu + S, Cq);
                S  = Su + S;
            }
        }
        float thk = fmaxf(y + S, Cq);
        y = __shfl(thk, 63, 64);

        if (o < NT) {
            T[o] = thk;
            C[o] = j;
        }
    }
}

extern "C" void kernel_launch(void* const* d_in, const int* in_sizes, int n_in,
                              void* d_out, int out_size, void* d_ws, size_t ws_size,
                              hipStream_t stream) {
    const float* Cv   = (const float*)d_in[0];
    const float* K    = (const float*)d_in[1];
    const float* jmin = (const float*)d_in[2];
    const float* W1   = (const float*)d_in[3];
    const float* b1   = (const float*)d_in[4];
    const float* W2   = (const float*)d_in[5];
    const float* b2   = (const float*)d_in[6];
    const float* W3   = (const float*)d_in[7];
    const float* b3   = (const float*)d_in[8];
    float* out = (float*)d_out;
    float* tbl = (float*)d_ws;                                // 32 KB
    int*   ncA = (int*)((char*)d_ws + TBL_N * sizeof(float)); // 16 KB

    prep<<<TBLOCKS + FILLB + NCB, 256, 0, stream>>>(
        W1, b1, W2, b2, W3, b3, K, tbl, ncA, out);
    res_solve<<<BATCH / 4, 256, 0, stream>>>(Cv, jmin, ncA, tbl, out);
    expand<<<BATCH / 4, 256, 0, stream>>>(Cv, jmin, ncA, out);
}

// Round 10
// 94.281 us; speedup vs baseline: 2.3493x; 1.0922x over previous
//
#include <hip/hip_runtime.h>

#define NT      2000
#define BATCH   4096
#define NODES   64
#define TBL_N   8192
#define JMAX    3.6f
#define TBLOCKS (TBL_N / 256)
#define NCB     (BATCH / 256)            // 16 nc-compute blocks
#define MAXIT   24

// ---------------- MLP evaluation helper (build phase only) ----------------
__device__ __forceinline__ float mlp_rho(float j,
    const float* sW1, const float* sB1, const float* sW2,
    const float* sB2, const float* sW3, float b3v) {
    float h1[NODES];
#pragma unroll
    for (int k = 0; k < NODES; ++k)
        h1[k] = fmaxf(fmaf(j, sW1[k], sB1[k]), 0.0f);
    float rho = b3v;
    for (int nt = 0; nt < NODES; nt += 8) {
        float acc[8];
#pragma unroll
        for (int q = 0; q < 8; ++q) acc[q] = sB2[nt + q];
#pragma unroll
        for (int k = 0; k < NODES; ++k) {
            float a = h1[k];
#pragma unroll
            for (int q = 0; q < 8; ++q)
                acc[q] = fmaf(a, sW2[k * NODES + nt + q], acc[q]);
        }
#pragma unroll
        for (int q = 0; q < 8; ++q)
            rho = fmaf(fmaxf(acc[q], 0.0f), sW3[nt + q], rho);
    }
    return rho;
}

// kernel 1: [0,32) rho table · [32,48) nc per chain
__global__ __launch_bounds__(256) void prep(
    const float* __restrict__ W1, const float* __restrict__ b1,
    const float* __restrict__ W2, const float* __restrict__ b2,
    const float* __restrict__ W3, const float* __restrict__ b3,
    const float* __restrict__ K,
    float* __restrict__ tbl, int* __restrict__ ncArr) {
    if (blockIdx.x < TBLOCKS) {
        __shared__ float sW2[NODES * NODES];
        __shared__ float sW1[NODES], sB1[NODES], sB2[NODES], sW3[NODES];
        __shared__ float sB3;
        for (int i = threadIdx.x; i < NODES * NODES; i += 256) sW2[i] = W2[i];
        if (threadIdx.x < NODES) {
            sW1[threadIdx.x] = W1[threadIdx.x];
            sB1[threadIdx.x] = b1[threadIdx.x];
            sB2[threadIdx.x] = b2[threadIdx.x];
            sW3[threadIdx.x] = W3[threadIdx.x];
        }
        if (threadIdx.x == 0) sB3 = b3[0];
        __syncthreads();
        int idx = blockIdx.x * 256 + threadIdx.x;
        const float h = JMAX / (float)TBL_N;
        tbl[idx] = mlp_rho(h * (float)idx, sW1, sB1, sW2, sB2, sW3, sB3);
    } else {
        int b = (blockIdx.x - TBLOCKS) * 256 + threadIdx.x;
        float Qmin = 3.3068376f * powf(K[b], 1.3333334f);
        int nc = 1 << 20;
        float Q = 0.0f;
        for (int o = 1; o <= 360; ++o) {
            float BC = 0.1f * (float)o;
            float jc = (0.14f * BC) * 0.125f;   // res == 50 exactly pre-cross
            Q = fmaf(jc, 0.1f, Q);
            if (Q > Qmin) { nc = o; break; }
        }
        ncArr[b] = min(nc, NT - 1);
    }
}

// kernel 2: fused parallel-in-time solve + expansion.
// One wave per chain, 64 time-steps per chunk. Per chunk: Picard-iterate the
// res recurrence (clamped-prefix (S,C) scan per sweep), then one thk scan,
// then coalesced stores of all four output planes.
__global__ __launch_bounds__(256) void fused(
    const float* __restrict__ Cv, const float* __restrict__ jmin,
    const int* __restrict__ ncArr, const float* __restrict__ tbl,
    float* __restrict__ out) {
    __shared__ float stbl[TBL_N];    // 32 KB
    for (int i = threadIdx.x; i < TBL_N / 4; i += 256)
        reinterpret_cast<float4*>(stbl)[i] =
            reinterpret_cast<const float4*>(tbl)[i];
    __syncthreads();

    const int lane = threadIdx.x & 63;
    const int b = blockIdx.x * 4 + (threadIdx.x >> 6);
    const float cv = Cv[b];
    const float jm = jmin[b];
    const int   nc = ncArr[b];
    const float k1   = cv * 0.1f;            // cv*DT (scales rho for res inc)
    const float invh = (float)TBL_N / JMAX;

    float* __restrict__ oT  = out + (size_t)b * NT;
    float* __restrict__ oR  = out + (size_t)BATCH * NT + (size_t)b * NT;
    float* __restrict__ oC  = out + 2 * (size_t)BATCH * NT + (size_t)b * NT;
    float* __restrict__ oTm = out + 3 * (size_t)BATCH * NT + (size_t)b * NT;

    const int NCH = (NT + 63) >> 6;          // 32 chunks
    float carry = 50.0f, slope = 0.0f;       // res carry/extrapolation slope
    float y = 0.0f;                          // thk carry

    for (int c = 0; c < NCH; ++c) {
        const int o = (c << 6) + lane;
        const bool valid = (o < NT);
        const float tm = 0.1f * (float)o;

        if ((c << 6) + 63 < nc) {
            // closed-form pre-crossing chunk
            float jc = (o == 0) ? 1e-3f : 0.00175f * (float)o;
            oT[o]  = 0.0f;
            oR[o]  = 50.0f;
            oC[o]  = jc;
            oTm[o] = tm;
            continue;
        }

        const bool act = (o >= nc) && valid;
        const float co = 0.14f * tm;          // matches reference rounding
        float res_g = fmaf(slope, (float)(lane + 1), carry);

        for (int it = 0; it < MAXIT; ++it) {
            float resp = __shfl_up(res_g, 1, 64);
            if (lane == 0) resp = carry;
            float jc = co * __builtin_amdgcn_rcpf(fmaf(0.14f, resp, 1.0f));
            float x = fminf(fmaxf(jc * invh, 0.0f), (float)(TBL_N - 2));
            int ip = (int)x;
            float fr = x - (float)ip;
            float t0 = stbl[ip], t1 = stbl[ip + 1];
            float rho = fmaf(fr, t1 - t0, t0);
            float inc = rho * k1 * (jc - jm);

            float S = act ? inc : 0.0f;
            float C = act ? 50.0f : -3.0e38f;
#pragma unroll
            for (int m = 1; m < 64; m <<= 1) {
                float Su = __shfl_up(S, m, 64);
                float Cu = __shfl_up(C, m, 64);
                if (lane >= m) { C = fmaxf(Cu + S, C); S = Su + S; }
            }
            float rn = fmaxf(carry + S, C);
            float d = fabsf(rn - res_g);
            res_g = rn;
            if (__all(d <= 1.0e-3f)) break;
        }

        // final j consistent with converged res
        float resp = __shfl_up(res_g, 1, 64);
        if (lane == 0) resp = carry;
        float jc = co * __builtin_amdgcn_rcpf(fmaf(0.14f, resp, 1.0f));

        // thk clamped-prefix scan: map y -> max(y + cvDT*(jc-jm), 0) if active
        float S2 = act ? k1 * (jc - jm) : 0.0f;
        float C2 = act ? 0.0f : -3.0e38f;
#pragma unroll
        for (int m = 1; m < 64; m <<= 1) {
            float Su = __shfl_up(S2, m, 64);
            float Cu = __shfl_up(C2, m, 64);
            if (lane >= m) { C2 = fmaxf(Cu + S2, C2); S2 = Su + S2; }
        }
        float thk = fmaxf(y + S2, C2);

        if (valid) {
            oT[o]  = thk;
            oR[o]  = res_g;
            oC[o]  = jc;
            oTm[o] = tm;
        }

        float lastR = __shfl(res_g, 63, 64);
        slope = (lastR - carry) * 0.015625f;
        carry = lastR;
        y = __shfl(thk, 63, 64);
    }
}

extern "C" void kernel_launch(void* const* d_in, const int* in_sizes, int n_in,
                              void* d_out, int out_size, void* d_ws, size_t ws_size,
                              hipStream_t stream) {
    const float* Cv   = (const float*)d_in[0];
    const float* K    = (const float*)d_in[1];
    const float* jmin = (const float*)d_in[2];
    const float* W1   = (const float*)d_in[3];
    const float* b1   = (const float*)d_in[4];
    const float* W2   = (const float*)d_in[5];
    const float* b2   = (const float*)d_in[6];
    const float* W3   = (const float*)d_in[7];
    const float* b3   = (const float*)d_in[8];
    float* out = (float*)d_out;
    float* tbl = (float*)d_ws;                                // 32 KB
    int*   ncA = (int*)((char*)d_ws + TBL_N * sizeof(float)); // 16 KB

    prep<<<TBLOCKS + NCB, 256, 0, stream>>>(W1, b1, W2, b2, W3, b3, K, tbl, ncA);
    fused<<<BATCH / 4, 256, 0, stream>>>(Cv, jmin, ncA, tbl, out);
}

// Round 11
// 92.834 us; speedup vs baseline: 2.3860x; 1.0156x over previous
//
#include <hip/hip_runtime.h>

#define NT      2000
#define BATCH   4096
#define NODES   64
#define TBL_N   8192
#define JMAX    3.6f
#define TBLOCKS (TBL_N / 256)
#define NCB     (BATCH / 256)            // 16 nc-compute blocks
#define MAXIT   24

// ---------------- MLP evaluation helper (build phase only) ----------------
__device__ __forceinline__ float mlp_rho(float j,
    const float* sW1, const float* sB1, const float* sW2,
    const float* sB2, const float* sW3, float b3v) {
    float h1[NODES];
#pragma unroll
    for (int k = 0; k < NODES; ++k)
        h1[k] = fmaxf(fmaf(j, sW1[k], sB1[k]), 0.0f);
    float rho = b3v;
    for (int nt = 0; nt < NODES; nt += 8) {
        float acc[8];
#pragma unroll
        for (int q = 0; q < 8; ++q) acc[q] = sB2[nt + q];
#pragma unroll
        for (int k = 0; k < NODES; ++k) {
            float a = h1[k];
#pragma unroll
            for (int q = 0; q < 8; ++q)
                acc[q] = fmaf(a, sW2[k * NODES + nt + q], acc[q]);
        }
#pragma unroll
        for (int q = 0; q < 8; ++q)
            rho = fmaf(fmaxf(acc[q], 0.0f), sW3[nt + q], rho);
    }
    return rho;
}

// kernel 1: [0,32) rho table · [32,48) nc per chain
__global__ __launch_bounds__(256) void prep(
    const float* __restrict__ W1, const float* __restrict__ b1,
    const float* __restrict__ W2, const float* __restrict__ b2,
    const float* __restrict__ W3, const float* __restrict__ b3,
    const float* __restrict__ K,
    float* __restrict__ tbl, int* __restrict__ ncArr) {
    if (blockIdx.x < TBLOCKS) {
        __shared__ float sW2[NODES * NODES];
        __shared__ float sW1[NODES], sB1[NODES], sB2[NODES], sW3[NODES];
        __shared__ float sB3;
        for (int i = threadIdx.x; i < NODES * NODES; i += 256) sW2[i] = W2[i];
        if (threadIdx.x < NODES) {
            sW1[threadIdx.x] = W1[threadIdx.x];
            sB1[threadIdx.x] = b1[threadIdx.x];
            sB2[threadIdx.x] = b2[threadIdx.x];
            sW3[threadIdx.x] = W3[threadIdx.x];
        }
        if (threadIdx.x == 0) sB3 = b3[0];
        __syncthreads();
        int idx = blockIdx.x * 256 + threadIdx.x;
        const float h = JMAX / (float)TBL_N;
        tbl[idx] = mlp_rho(h * (float)idx, sW1, sB1, sW2, sB2, sW3, sB3);
    } else {
        int b = (blockIdx.x - TBLOCKS) * 256 + threadIdx.x;
        float Qmin = 3.3068376f * powf(K[b], 1.3333334f);
        int nc = 1 << 20;
        float Q = 0.0f;
        for (int o = 1; o <= 360; ++o) {
            float BC = 0.1f * (float)o;
            float jc = (0.14f * BC) * 0.125f;   // res == 50 exactly pre-cross
            Q = fmaf(jc, 0.1f, Q);
            if (Q > Qmin) { nc = o; break; }
        }
        ncArr[b] = min(nc, NT - 1);
    }
}

// kernel 2: fused parallel-in-time solve + expansion (one wave per chain).
__global__ __launch_bounds__(256) void fused(
    const float* __restrict__ Cv, const float* __restrict__ jmin,
    const int* __restrict__ ncArr, const float* __restrict__ tbl,
    float* __restrict__ out) {
    __shared__ float stbl[TBL_N];    // 32 KB
    for (int i = threadIdx.x; i < TBL_N / 4; i += 256)
        reinterpret_cast<float4*>(stbl)[i] =
            reinterpret_cast<const float4*>(tbl)[i];
    __syncthreads();

    const int lane = threadIdx.x & 63;
    const int b = blockIdx.x * 4 + (threadIdx.x >> 6);
    const float cv = Cv[b];
    const float jm = jmin[b];
    const int   nc = ncArr[b];
    const float k1   = cv * 0.1f;            // cv*DT
    const float nk1jm = -k1 * jm;
    const float invh = (float)TBL_N / JMAX;
    const float l1   = (float)(lane + 1);
    const float l1sq = l1 * l1;

    float* __restrict__ oT  = out + (size_t)b * NT;
    float* __restrict__ oR  = out + (size_t)BATCH * NT + (size_t)b * NT;
    float* __restrict__ oC  = out + 2 * (size_t)BATCH * NT + (size_t)b * NT;
    float* __restrict__ oTm = out + 3 * (size_t)BATCH * NT + (size_t)b * NT;

    const int NCH = (NT + 63) >> 6;          // 32 chunks (last partial: 2000)
    float carry = 50.0f, slope = 0.0f, curv = 0.0f;
    float y = 0.0f;                          // thk carry

    for (int c = 0; c < NCH; ++c) {
        const int o = (c << 6) + lane;
        const bool valid = (o < NT);
        const float tm = 0.1f * (float)o;

        if ((c << 6) + 63 < nc) {            // closed-form pre-crossing chunk
            float jc = (o == 0) ? 1e-3f : 0.00175f * (float)o;
            oT[o]  = 0.0f;
            oR[o]  = 50.0f;
            oC[o]  = jc;
            oTm[o] = tm;
            continue;
        }

        const bool act = (o >= nc) && valid;
        const float co = 0.14f * tm;          // matches reference rounding
        // quadratic warm start
        float res_g = fmaf(curv, l1sq, fmaf(slope, l1, carry));

        float jc_f = 0.0f, tinc_f = 0.0f;
        for (int it = 0; it < MAXIT; ++it) {
            float resp = __shfl_up(res_g, 1, 64);
            if (lane == 0) resp = carry;
            float jc = co * __builtin_amdgcn_rcpf(fmaf(0.14f, resp, 1.0f));
            float x = fminf(fmaxf(jc * invh, 0.0f), (float)(TBL_N - 2));
            int ip = (int)x;
            float fr = x - (float)ip;
            float t0 = stbl[ip], t1 = stbl[ip + 1];
            float rho = fmaf(fr, t1 - t0, t0);
            float tinc = fmaf(k1, jc, nk1jm);         // cvDT*(jc-jm)
            float inc = act ? rho * tinc : 0.0f;
            jc_f = jc; tinc_f = tinc;

            // plain prefix-sum (6 shfl)
            float S = inc;
#pragma unroll
            for (int m = 1; m < 64; m <<= 1) {
                float Su = __shfl_up(S, m, 64);
                if (lane >= m) S += Su;
            }
            float rn = carry + S;
            if (!__all(rn >= 50.0f)) {
                // clamp binds somewhere: exact (S,C) scan
                float S3 = inc;
                float C3 = act ? 50.0f : -3.0e38f;
#pragma unroll
                for (int m = 1; m < 64; m <<= 1) {
                    float Su = __shfl_up(S3, m, 64);
                    float Cu = __shfl_up(C3, m, 64);
                    if (lane >= m) { C3 = fmaxf(Cu + S3, C3); S3 = Su + S3; }
                }
                rn = fmaxf(carry + S3, C3);
            }
            float d = fabsf(rn - res_g);
            res_g = rn;
            if (__all(d <= 1.0e-3f)) break;
        }

        // thk: prefix of tinc (clamp at 0 almost never binds)
        float S2 = act ? tinc_f : 0.0f;
        {
            float S = S2;
#pragma unroll
            for (int m = 1; m < 64; m <<= 1) {
                float Su = __shfl_up(S, m, 64);
                if (lane >= m) S += Su;
            }
            float tn = y + S;
            if (!__all(tn >= 0.0f)) {
                float S4 = S2;
                float C4 = act ? 0.0f : -3.0e38f;
#pragma unroll
                for (int m = 1; m < 64; m <<= 1) {
                    float Su = __shfl_up(S4, m, 64);
                    float Cu = __shfl_up(C4, m, 64);
                    if (lane >= m) { C4 = fmaxf(Cu + S4, C4); S4 = Su + S4; }
                }
                tn = fmaxf(y + S4, C4);
            }
            S2 = tn;
        }
        float thk = S2;

        if (valid) {
            oT[o]  = thk;
            oR[o]  = res_g;
            oC[o]  = jc_f;
            oTm[o] = tm;
        }

        float lastR = __shfl(res_g, 63, 64);
        float ns = (lastR - carry) * 0.015625f;       // per-step slope
        curv = (ns - slope) * 0.0078125f;             // 0.5/64 per-step^2
        slope = ns;
        carry = lastR;
        y = __shfl(thk, 63, 64);
    }
}

extern "C" void kernel_launch(void* const* d_in, const int* in_sizes, int n_in,
                              void* d_out, int out_size, void* d_ws, size_t ws_size,
                              hipStream_t stream) {
    const float* Cv   = (const float*)d_in[0];
    const float* K    = (const float*)d_in[1];
    const float* jmin = (const float*)d_in[2];
    const float* W1   = (const float*)d_in[3];
    const float* b1   = (const float*)d_in[4];
    const float* W2   = (const float*)d_in[5];
    const float* b2   = (const float*)d_in[6];
    const float* W3   = (const float*)d_in[7];
    const float* b3   = (const float*)d_in[8];
    float* out = (float*)d_out;
    float* tbl = (float*)d_ws;                                // 32 KB
    int*   ncA = (int*)((char*)d_ws + TBL_N * sizeof(float)); // 16 KB

    prep<<<TBLOCKS + NCB, 256, 0, stream>>>(W1, b1, W2, b2, W3, b3, K, tbl, ncA);
    fused<<<BATCH / 4, 256, 0, stream>>>(Cv, jmin, ncA, tbl, out);
}

// Round 12
// 75.456 us; speedup vs baseline: 2.9355x; 1.2303x over previous
//
#include <hip/hip_runtime.h>

#define NT      2000
#define BATCH   4096
#define NODES   64
#define TBL_N   8192
#define JMAX    3.6f
#define TBLOCKS (TBL_N / 256)
#define NCB     (BATCH / 256)            // 16 nc-compute blocks
#define MAXIT   24

// ---------------- DPP cross-lane helpers (VALU, no DS latency) ----------------
// update_dpp: lanes with invalid source keep `oldv`. CTRL: row_shr:m = 0x110+m,
// row_bcast15 = 0x142, row_bcast31 = 0x143, wave_shr:1 = 0x138 (gfx9 lineage).
template<int CTRL, int RMASK>
__device__ __forceinline__ float updpp(float oldv, float x) {
    return __int_as_float(__builtin_amdgcn_update_dpp(
        __float_as_int(oldv), __float_as_int(x), CTRL, RMASK, 0xF, false));
}

// inclusive clamped-prefix (S,C) scan over the 64-lane wave.
// compose(left,right): S = Sl+Sr ; C = max(Cl+Sr, Cr).
__device__ __forceinline__ void scan_sc(float& S, float& C) {
    const float NI = -3.0e38f;
    float Su, Cu;
    Su = updpp<0x111, 0xF>(0.0f, S); Cu = updpp<0x111, 0xF>(NI, C);
    C = fmaxf(Cu + S, C); S = Su + S;
    Su = updpp<0x112, 0xF>(0.0f, S); Cu = updpp<0x112, 0xF>(NI, C);
    C = fmaxf(Cu + S, C); S = Su + S;
    Su = updpp<0x114, 0xF>(0.0f, S); Cu = updpp<0x114, 0xF>(NI, C);
    C = fmaxf(Cu + S, C); S = Su + S;
    Su = updpp<0x118, 0xF>(0.0f, S); Cu = updpp<0x118, 0xF>(NI, C);
    C = fmaxf(Cu + S, C); S = Su + S;
    Su = updpp<0x142, 0xA>(0.0f, S); Cu = updpp<0x142, 0xA>(NI, C);
    C = fmaxf(Cu + S, C); S = Su + S;
    Su = updpp<0x143, 0xC>(0.0f, S); Cu = updpp<0x143, 0xC>(NI, C);
    C = fmaxf(Cu + S, C); S = Su + S;
}

// ---------------- MLP evaluation helper (build phase only) ----------------
__device__ __forceinline__ float mlp_rho(float j,
    const float* sW1, const float* sB1, const float* sW2,
    const float* sB2, const float* sW3, float b3v) {
    float h1[NODES];
#pragma unroll
    for (int k = 0; k < NODES; ++k)
        h1[k] = fmaxf(fmaf(j, sW1[k], sB1[k]), 0.0f);
    float rho = b3v;
    for (int nt = 0; nt < NODES; nt += 8) {
        float acc[8];
#pragma unroll
        for (int q = 0; q < 8; ++q) acc[q] = sB2[nt + q];
#pragma unroll
        for (int k = 0; k < NODES; ++k) {
            float a = h1[k];
#pragma unroll
            for (int q = 0; q < 8; ++q)
                acc[q] = fmaf(a, sW2[k * NODES + nt + q], acc[q]);
        }
#pragma unroll
        for (int q = 0; q < 8; ++q)
            rho = fmaf(fmaxf(acc[q], 0.0f), sW3[nt + q], rho);
    }
    return rho;
}

// kernel 1: [0,32) rho table · [32,48) nc per chain
__global__ __launch_bounds__(256) void prep(
    const float* __restrict__ W1, const float* __restrict__ b1,
    const float* __restrict__ W2, const float* __restrict__ b2,
    const float* __restrict__ W3, const float* __restrict__ b3,
    const float* __restrict__ K,
    float* __restrict__ tbl, int* __restrict__ ncArr) {
    if (blockIdx.x < TBLOCKS) {
        __shared__ float sW2[NODES * NODES];
        __shared__ float sW1[NODES], sB1[NODES], sB2[NODES], sW3[NODES];
        __shared__ float sB3;
        for (int i = threadIdx.x; i < NODES * NODES; i += 256) sW2[i] = W2[i];
        if (threadIdx.x < NODES) {
            sW1[threadIdx.x] = W1[threadIdx.x];
            sB1[threadIdx.x] = b1[threadIdx.x];
            sB2[threadIdx.x] = b2[threadIdx.x];
            sW3[threadIdx.x] = W3[threadIdx.x];
        }
        if (threadIdx.x == 0) sB3 = b3[0];
        __syncthreads();
        int idx = blockIdx.x * 256 + threadIdx.x;
        const float h = JMAX / (float)TBL_N;
        tbl[idx] = mlp_rho(h * (float)idx, sW1, sB1, sW2, sB2, sW3, sB3);
    } else {
        int b = (blockIdx.x - TBLOCKS) * 256 + threadIdx.x;
        float Qmin = 3.3068376f * powf(K[b], 1.3333334f);
        int nc = 1 << 20;
        float Q = 0.0f;
        for (int o = 1; o <= 360; ++o) {
            float BC = 0.1f * (float)o;
            float jc = (0.14f * BC) * 0.125f;   // res == 50 exactly pre-cross
            Q = fmaf(jc, 0.1f, Q);
            if (Q > Qmin) { nc = o; break; }
        }
        ncArr[b] = min(nc, NT - 1);
    }
}

// kernel 2: fused parallel-in-time solve + expansion (one wave per chain).
__global__ __launch_bounds__(256) void fused(
    const float* __restrict__ Cv, const float* __restrict__ jmin,
    const int* __restrict__ ncArr, const float* __restrict__ tbl,
    float* __restrict__ out) {
    __shared__ float stbl[TBL_N];    // 32 KB
    for (int i = threadIdx.x; i < TBL_N / 4; i += 256)
        reinterpret_cast<float4*>(stbl)[i] =
            reinterpret_cast<const float4*>(tbl)[i];
    __syncthreads();

    const int lane = threadIdx.x & 63;
    const int b = blockIdx.x * 4 + (threadIdx.x >> 6);
    const float cv = Cv[b];
    const float jm = jmin[b];
    const int   nc = ncArr[b];
    const float k1    = cv * 0.1f;           // cv*DT
    const float nk1jm = -k1 * jm;
    const float invh  = (float)TBL_N / JMAX;
    const float l1    = (float)(lane + 1);
    const float l1sq  = l1 * l1;

    float* __restrict__ oT  = out + (size_t)b * NT;
    float* __restrict__ oR  = out + (size_t)BATCH * NT + (size_t)b * NT;
    float* __restrict__ oC  = out + 2 * (size_t)BATCH * NT + (size_t)b * NT;
    float* __restrict__ oTm = out + 3 * (size_t)BATCH * NT + (size_t)b * NT;

    const int NCH = (NT + 63) >> 6;          // 32 chunks
    float carry = 50.0f, slope = 0.0f, curv = 0.0f;
    float y = 0.0f;                          // thk carry

    for (int c = 0; c < NCH; ++c) {
        const int o = (c << 6) + lane;
        const bool valid = (o < NT);
        const float tm = 0.1f * (float)o;

        if ((c << 6) + 63 < nc) {            // closed-form pre-crossing chunk
            float jc = (o == 0) ? 1e-3f : 0.00175f * (float)o;
            oT[o]  = 0.0f;
            oR[o]  = 50.0f;
            oC[o]  = jc;
            oTm[o] = tm;
            continue;
        }

        const bool act = (o >= nc) && valid;
        const float co = 0.14f * tm;          // matches reference rounding
        float res_g = fmaf(curv, l1sq, fmaf(slope, l1, carry));

        float jc_f = 0.0f, tinc_f = 0.0f;
        for (int it = 0; it < MAXIT; ++it) {
            float resp = updpp<0x138, 0xF>(carry, res_g);   // wave_shr:1
            float jc = co * __builtin_amdgcn_rcpf(fmaf(0.14f, resp, 1.0f));
            float x = fminf(fmaxf(jc * invh, 0.0f), (float)(TBL_N - 2));
            int ip = (int)x;
            float fr = x - (float)ip;
            float t0 = stbl[ip], t1 = stbl[ip + 1];
            float rho = fmaf(fr, t1 - t0, t0);
            float tinc = fmaf(k1, jc, nk1jm);               // cvDT*(jc-jm)
            jc_f = jc; tinc_f = tinc;

            float S = act ? rho * tinc : 0.0f;
            float C = act ? 50.0f : -3.0e38f;
            scan_sc(S, C);
            float rn = fmaxf(carry + S, C);
            float d = fabsf(rn - res_g);
            res_g = rn;
            if (__all(d <= 1.0e-3f)) break;
        }

        // thk clamped-prefix scan (same converged jc)
        float S2 = act ? tinc_f : 0.0f;
        float C2 = act ? 0.0f : -3.0e38f;
        scan_sc(S2, C2);
        float thk = fmaxf(y + S2, C2);

        if (valid) {
            oT[o]  = thk;
            oR[o]  = res_g;
            oC[o]  = jc_f;
            oTm[o] = tm;
        }

        float lastR = __shfl(res_g, 63, 64);
        float ns = (lastR - carry) * 0.015625f;
        curv = (ns - slope) * 0.0078125f;
        slope = ns;
        carry = lastR;
        y = __shfl(thk, 63, 64);
    }
}

extern "C" void kernel_launch(void* const* d_in, const int* in_sizes, int n_in,
                              void* d_out, int out_size, void* d_ws, size_t ws_size,
                              hipStream_t stream) {
    const float* Cv   = (const float*)d_in[0];
    const float* K    = (const float*)d_in[1];
    const float* jmin = (const float*)d_in[2];
    const float* W1   = (const float*)d_in[3];
    const float* b1   = (const float*)d_in[4];
    const float* W2   = (const float*)d_in[5];
    const float* b2   = (const float*)d_in[6];
    const float* W3   = (const float*)d_in[7];
    const float* b3   = (const float*)d_in[8];
    float* out = (float*)d_out;
    float* tbl = (float*)d_ws;                                // 32 KB
    int*   ncA = (int*)((char*)d_ws + TBL_N * sizeof(float)); // 16 KB

    prep<<<TBLOCKS + NCB, 256, 0, stream>>>(W1, b1, W2, b2, W3, b3, K, tbl, ncA);
    fused<<<BATCH / 4, 256, 0, stream>>>(Cv, jmin, ncA, tbl, out);
}

// Round 13
// 70.942 us; speedup vs baseline: 3.1222x; 1.0636x over previous
//
#include <hip/hip_runtime.h>

#define NT      2000
#define BATCH   4096
#define NODES   64
#define TBL_N   8192
#define JMAX    3.6f
#define TBLOCKS (TBL_N / 256)
#define NCB     (BATCH / 256)
#define MAXIT   24
#define CHUNKS  ((NT + 255) / 256)       // 8 chunks of 256 steps (4/lane)

// ---------------- DPP cross-lane helpers (VALU, no DS latency) ----------------
template<int CTRL, int RMASK>
__device__ __forceinline__ float updpp(float oldv, float x) {
    return __int_as_float(__builtin_amdgcn_update_dpp(
        __float_as_int(oldv), __float_as_int(x), CTRL, RMASK, 0xF, false));
}
__device__ __forceinline__ float rdl63(float v) {
    return __int_as_float(__builtin_amdgcn_readlane(__float_as_int(v), 63));
}

// inclusive clamped-prefix (S,C) scan over the 64-lane wave.
// compose(left,right): S = Sl+Sr ; C = max(Cl+Sr, Cr).
__device__ __forceinline__ void scan_sc(float& S, float& C) {
    const float NI = -3.0e38f;
    float Su, Cu;
    Su = updpp<0x111, 0xF>(0.0f, S); Cu = updpp<0x111, 0xF>(NI, C);
    C = fmaxf(Cu + S, C); S = Su + S;
    Su = updpp<0x112, 0xF>(0.0f, S); Cu = updpp<0x112, 0xF>(NI, C);
    C = fmaxf(Cu + S, C); S = Su + S;
    Su = updpp<0x114, 0xF>(0.0f, S); Cu = updpp<0x114, 0xF>(NI, C);
    C = fmaxf(Cu + S, C); S = Su + S;
    Su = updpp<0x118, 0xF>(0.0f, S); Cu = updpp<0x118, 0xF>(NI, C);
    C = fmaxf(Cu + S, C); S = Su + S;
    Su = updpp<0x142, 0xA>(0.0f, S); Cu = updpp<0x142, 0xA>(NI, C);
    C = fmaxf(Cu + S, C); S = Su + S;
    Su = updpp<0x143, 0xC>(0.0f, S); Cu = updpp<0x143, 0xC>(NI, C);
    C = fmaxf(Cu + S, C); S = Su + S;
}

// ---------------- MLP evaluation helper (build phase only) ----------------
__device__ __forceinline__ float mlp_rho(float j,
    const float* sW1, const float* sB1, const float* sW2,
    const float* sB2, const float* sW3, float b3v) {
    float h1[NODES];
#pragma unroll
    for (int k = 0; k < NODES; ++k)
        h1[k] = fmaxf(fmaf(j, sW1[k], sB1[k]), 0.0f);
    float rho = b3v;
    for (int nt = 0; nt < NODES; nt += 8) {
        float acc[8];
#pragma unroll
        for (int q = 0; q < 8; ++q) acc[q] = sB2[nt + q];
#pragma unroll
        for (int k = 0; k < NODES; ++k) {
            float a = h1[k];
#pragma unroll
            for (int q = 0; q < 8; ++q)
                acc[q] = fmaf(a, sW2[k * NODES + nt + q], acc[q]);
        }
#pragma unroll
        for (int q = 0; q < 8; ++q)
            rho = fmaf(fmaxf(acc[q], 0.0f), sW3[nt + q], rho);
    }
    return rho;
}

// kernel 1: [0,32) rho table · [32,48) nc per chain
__global__ __launch_bounds__(256) void prep(
    const float* __restrict__ W1, const float* __restrict__ b1,
    const float* __restrict__ W2, const float* __restrict__ b2,
    const float* __restrict__ W3, const float* __restrict__ b3,
    const float* __restrict__ K,
    float* __restrict__ tbl, int* __restrict__ ncArr) {
    if (blockIdx.x < TBLOCKS) {
        __shared__ float sW2[NODES * NODES];
        __shared__ float sW1[NODES], sB1[NODES], sB2[NODES], sW3[NODES];
        __shared__ float sB3;
        for (int i = threadIdx.x; i < NODES * NODES; i += 256) sW2[i] = W2[i];
        if (threadIdx.x < NODES) {
            sW1[threadIdx.x] = W1[threadIdx.x];
            sB1[threadIdx.x] = b1[threadIdx.x];
            sB2[threadIdx.x] = b2[threadIdx.x];
            sW3[threadIdx.x] = W3[threadIdx.x];
        }
        if (threadIdx.x == 0) sB3 = b3[0];
        __syncthreads();
        int idx = blockIdx.x * 256 + threadIdx.x;
        const float h = JMAX / (float)TBL_N;
        tbl[idx] = mlp_rho(h * (float)idx, sW1, sB1, sW2, sB2, sW3, sB3);
    } else {
        int b = (blockIdx.x - TBLOCKS) * 256 + threadIdx.x;
        float Qmin = 3.3068376f * powf(K[b], 1.3333334f);
        int nc = 1 << 20;
        float Q = 0.0f;
        for (int o = 1; o <= 360; ++o) {
            float BC = 0.1f * (float)o;
            float jc = (0.14f * BC) * 0.125f;
            Q = fmaf(jc, 0.1f, Q);
            if (Q > Qmin) { nc = o; break; }
        }
        ncArr[b] = min(nc, NT - 1);
    }
}

// kernel 2: fused parallel-in-time solve + expansion.
// One wave per chain; 4 steps per lane; 256-step chunks; 8 chunks.
__global__ __launch_bounds__(256) void fused(
    const float* __restrict__ Cv, const float* __restrict__ jmin,
    const int* __restrict__ ncArr, const float* __restrict__ tbl,
    float* __restrict__ out) {
    __shared__ float stbl[TBL_N];    // 32 KB
    for (int i = threadIdx.x; i < TBL_N / 4; i += 256)
        reinterpret_cast<float4*>(stbl)[i] =
            reinterpret_cast<const float4*>(tbl)[i];
    __syncthreads();

    const float NI = -3.0e38f;
    const int lane = threadIdx.x & 63;
    const int b = blockIdx.x * 4 + (threadIdx.x >> 6);
    const float cv = Cv[b];
    const float jm = jmin[b];
    const int   nc = ncArr[b];
    const float k1    = cv * 0.1f;
    const float nk1jm = -k1 * jm;
    const float invh  = (float)TBL_N / JMAX;

    float* __restrict__ oT  = out + (size_t)b * NT;
    float* __restrict__ oR  = out + (size_t)BATCH * NT + (size_t)b * NT;
    float* __restrict__ oC  = out + 2 * (size_t)BATCH * NT + (size_t)b * NT;
    float* __restrict__ oTm = out + 3 * (size_t)BATCH * NT + (size_t)b * NT;

    float carry = 50.0f, slope = 0.0f, curv = 0.0f;
    float y = 0.0f;

    for (int c = 0; c < CHUNKS; ++c) {
        const int ob = c << 8;
        const int o0 = ob + 4 * lane, o1 = o0 + 1, o2 = o0 + 2, o3 = o0 + 3;
        const float tm0 = 0.1f * (float)o0, tm1 = 0.1f * (float)o1;
        const float tm2 = 0.1f * (float)o2, tm3 = 0.1f * (float)o3;
        const float co0 = 0.14f * tm0, co1 = 0.14f * tm1;
        const float co2 = 0.14f * tm2, co3 = 0.14f * tm3;
        const bool a0 = (o0 >= nc) && (o0 < NT);
        const bool a1 = (o1 >= nc) && (o1 < NT);
        const bool a2 = (o2 >= nc) && (o2 < NT);
        const bool a3 = (o3 >= nc) && (o3 < NT);

        // quadratic warm start (s = step index within chunk, 1-based)
        const float s0 = (float)(4 * lane + 1);
        float g0 = fmaf(fmaf(curv, s0, slope), s0, carry);
        const float s1 = s0 + 1.0f;
        float g1 = fmaf(fmaf(curv, s1, slope), s1, carry);
        const float s2 = s0 + 2.0f;
        float g2 = fmaf(fmaf(curv, s2, slope), s2, carry);
        const float s3 = s0 + 3.0f;
        float g3 = fmaf(fmaf(curv, s3, slope), s3, carry);

        float j0, j1, j2, j3, n0, n1, n2, n3;
        for (int it = 0; it < MAXIT; ++it) {
            float rp0 = updpp<0x138, 0xF>(carry, g3);   // wave_shr1, lane0=carry
            float rp1 = g0, rp2 = g1, rp3 = g2;
            j0 = co0 * __builtin_amdgcn_rcpf(fmaf(0.14f, rp0, 1.0f));
            j1 = co1 * __builtin_amdgcn_rcpf(fmaf(0.14f, rp1, 1.0f));
            j2 = co2 * __builtin_amdgcn_rcpf(fmaf(0.14f, rp2, 1.0f));
            j3 = co3 * __builtin_amdgcn_rcpf(fmaf(0.14f, rp3, 1.0f));

            float x0 = fminf(fmaxf(j0 * invh, 0.0f), (float)(TBL_N - 2));
            float x1 = fminf(fmaxf(j1 * invh, 0.0f), (float)(TBL_N - 2));
            float x2 = fminf(fmaxf(j2 * invh, 0.0f), (float)(TBL_N - 2));
            float x3 = fminf(fmaxf(j3 * invh, 0.0f), (float)(TBL_N - 2));
            int ip0 = (int)x0, ip1 = (int)x1, ip2 = (int)x2, ip3 = (int)x3;
            float fr0 = x0 - (float)ip0, fr1 = x1 - (float)ip1;
            float fr2 = x2 - (float)ip2, fr3 = x3 - (float)ip3;
            float ta0 = stbl[ip0], tb0 = stbl[ip0 + 1];
            float ta1 = stbl[ip1], tb1 = stbl[ip1 + 1];
            float ta2 = stbl[ip2], tb2 = stbl[ip2 + 1];
            float ta3 = stbl[ip3], tb3 = stbl[ip3 + 1];
            float rho0 = fmaf(fr0, tb0 - ta0, ta0);
            float rho1 = fmaf(fr1, tb1 - ta1, ta1);
            float rho2 = fmaf(fr2, tb2 - ta2, ta2);
            float rho3 = fmaf(fr3, tb3 - ta3, ta3);

            n0 = fmaf(k1, j0, nk1jm); n1 = fmaf(k1, j1, nk1jm);
            n2 = fmaf(k1, j2, nk1jm); n3 = fmaf(k1, j3, nk1jm);
            float i0 = a0 ? rho0 * n0 : 0.0f;
            float i1 = a1 ? rho1 * n1 : 0.0f;
            float i2 = a2 ? rho2 * n2 : 0.0f;
            float i3 = a3 ? rho3 * n3 : 0.0f;
            float c0 = a0 ? 50.0f : NI, c1 = a1 ? 50.0f : NI;
            float c2 = a2 ? 50.0f : NI, c3 = a3 ? 50.0f : NI;

            // local inclusive prefixes (4 steps)
            float LS0 = i0,        LC0 = c0;
            float LS1 = LS0 + i1,  LC1 = fmaxf(LC0 + i1, c1);
            float LS2 = LS1 + i2,  LC2 = fmaxf(LC1 + i2, c2);
            float LS3 = LS2 + i3,  LC3 = fmaxf(LC2 + i3, c3);

            float Sw = LS3, Cw = LC3;
            scan_sc(Sw, Cw);
            float Se = updpp<0x138, 0xF>(0.0f, Sw);
            float Ce = updpp<0x138, 0xF>(NI, Cw);

            float r0 = fmaxf(carry + (Se + LS0), fmaxf(Ce + LS0, LC0));
            float r1 = fmaxf(carry + (Se + LS1), fmaxf(Ce + LS1, LC1));
            float r2 = fmaxf(carry + (Se + LS2), fmaxf(Ce + LS2, LC2));
            float r3 = fmaxf(carry + (Se + LS3), fmaxf(Ce + LS3, LC3));

            float d = fmaxf(fmaxf(fabsf(r0 - g0), fabsf(r1 - g1)),
                            fmaxf(fabsf(r2 - g2), fabsf(r3 - g3)));
            g0 = r0; g1 = r1; g2 = r2; g3 = r3;
            if (__all(d <= 1.0e-3f)) break;
        }

        // thk clamped-prefix over tinc (limit 0), same structure
        {
            float i0 = a0 ? n0 : 0.0f, i1 = a1 ? n1 : 0.0f;
            float i2 = a2 ? n2 : 0.0f, i3 = a3 ? n3 : 0.0f;
            float c0 = a0 ? 0.0f : NI, c1 = a1 ? 0.0f : NI;
            float c2 = a2 ? 0.0f : NI, c3 = a3 ? 0.0f : NI;
            float LS0 = i0,        LC0 = c0;
            float LS1 = LS0 + i1,  LC1 = fmaxf(LC0 + i1, c1);
            float LS2 = LS1 + i2,  LC2 = fmaxf(LC1 + i2, c2);
            float LS3 = LS2 + i3,  LC3 = fmaxf(LC2 + i3, c3);
            float Sw = LS3, Cw = LC3;
            scan_sc(Sw, Cw);
            float Se = updpp<0x138, 0xF>(0.0f, Sw);
            float Ce = updpp<0x138, 0xF>(NI, Cw);
            float t0 = fmaxf(y + (Se + LS0), fmaxf(Ce + LS0, LC0));
            float t1 = fmaxf(y + (Se + LS1), fmaxf(Ce + LS1, LC1));
            float t2 = fmaxf(y + (Se + LS2), fmaxf(Ce + LS2, LC2));
            float t3 = fmaxf(y + (Se + LS3), fmaxf(Ce + LS3, LC3));

            if (o0 == 0) j0 = 1e-3f;   // current[0] fixed value

            if (o3 < NT) {
                const int q = (ob >> 2) + lane;
                reinterpret_cast<float4*>(oT)[q]  = make_float4(t0, t1, t2, t3);
                reinterpret_cast<float4*>(oR)[q]  = make_float4(g0, g1, g2, g3);
                reinterpret_cast<float4*>(oC)[q]  = make_float4(j0, j1, j2, j3);
                reinterpret_cast<float4*>(oTm)[q] = make_float4(tm0, tm1, tm2, tm3);
            }
            y = rdl63(t3);
        }

        float lastR = rdl63(g3);
        float ns = (lastR - carry) * 0.00390625f;     // /256 per-step slope
        curv = (ns - slope) * 0.001953125f;           // 0.5/256
        slope = ns;
        carry = lastR;
    }
}

extern "C" void kernel_launch(void* const* d_in, const int* in_sizes, int n_in,
                              void* d_out, int out_size, void* d_ws, size_t ws_size,
                              hipStream_t stream) {
    const float* Cv   = (const float*)d_in[0];
    const float* K    = (const float*)d_in[1];
    const float* jmin = (const float*)d_in[2];
    const float* W1   = (const float*)d_in[3];
    const float* b1   = (const float*)d_in[4];
    const float* W2   = (const float*)d_in[5];
    const float* b2   = (const float*)d_in[6];
    const float* W3   = (const float*)d_in[7];
    const float* b3   = (const float*)d_in[8];
    float* out = (float*)d_out;
    float* tbl = (float*)d_ws;                                // 32 KB
    int*   ncA = (int*)((char*)d_ws + TBL_N * sizeof(float)); // 16 KB

    prep<<<TBLOCKS + NCB, 256, 0, stream>>>(W1, b1, W2, b2, W3, b3, K, tbl, ncA);
    fused<<<BATCH / 4, 256, 0, stream>>>(Cv, jmin, ncA, tbl, out);
}

// Round 14
// 70.766 us; speedup vs baseline: 3.1300x; 1.0025x over previous
//
#include <hip/hip_runtime.h>

#define NT      2000
#define BATCH   4096
#define NODES   64
#define TBL_N   8192
#define JMAX    3.6f
#define TBLOCKS (TBL_N / 256)
#define NCB     (BATCH / 256)            // 16 nc blocks
#define FILLB   (BATCH * NT / 4 / 256)   // 8000 time-plane blocks
#define MAXIT   24
#define CHUNKS  ((NT + 255) / 256)       // 8 chunks of 256 steps (4/lane)

// ---------------- DPP cross-lane helpers (VALU, no DS latency) ----------------
template<int CTRL, int RMASK>
__device__ __forceinline__ float updpp(float oldv, float x) {
    return __int_as_float(__builtin_amdgcn_update_dpp(
        __float_as_int(oldv), __float_as_int(x), CTRL, RMASK, 0xF, false));
}
__device__ __forceinline__ float rdl63(float v) {
    return __int_as_float(__builtin_amdgcn_readlane(__float_as_int(v), 63));
}

// inclusive clamped-prefix (S,C) scan over the 64-lane wave.
// compose(left,right): S = Sl+Sr ; C = max(Cl+Sr, Cr).
__device__ __forceinline__ void scan_sc(float& S, float& C) {
    const float NI = -3.0e38f;
    float Su, Cu;
    Su = updpp<0x111, 0xF>(0.0f, S); Cu = updpp<0x111, 0xF>(NI, C);
    C = fmaxf(Cu + S, C); S = Su + S;
    Su = updpp<0x112, 0xF>(0.0f, S); Cu = updpp<0x112, 0xF>(NI, C);
    C = fmaxf(Cu + S, C); S = Su + S;
    Su = updpp<0x114, 0xF>(0.0f, S); Cu = updpp<0x114, 0xF>(NI, C);
    C = fmaxf(Cu + S, C); S = Su + S;
    Su = updpp<0x118, 0xF>(0.0f, S); Cu = updpp<0x118, 0xF>(NI, C);
    C = fmaxf(Cu + S, C); S = Su + S;
    Su = updpp<0x142, 0xA>(0.0f, S); Cu = updpp<0x142, 0xA>(NI, C);
    C = fmaxf(Cu + S, C); S = Su + S;
    Su = updpp<0x143, 0xC>(0.0f, S); Cu = updpp<0x143, 0xC>(NI, C);
    C = fmaxf(Cu + S, C); S = Su + S;
}

// ---------------- MLP evaluation helper (build phase only) ----------------
__device__ __forceinline__ float mlp_rho(float j,
    const float* sW1, const float* sB1, const float* sW2,
    const float* sB2, const float* sW3, float b3v) {
    float h1[NODES];
#pragma unroll
    for (int k = 0; k < NODES; ++k)
        h1[k] = fmaxf(fmaf(j, sW1[k], sB1[k]), 0.0f);
    float rho = b3v;
    for (int nt = 0; nt < NODES; nt += 8) {
        float acc[8];
#pragma unroll
        for (int q = 0; q < 8; ++q) acc[q] = sB2[nt + q];
#pragma unroll
        for (int k = 0; k < NODES; ++k) {
            float a = h1[k];
#pragma unroll
            for (int q = 0; q < 8; ++q)
                acc[q] = fmaf(a, sW2[k * NODES + nt + q], acc[q]);
        }
#pragma unroll
        for (int q = 0; q < 8; ++q)
            rho = fmaf(fmaxf(acc[q], 0.0f), sW3[nt + q], rho);
    }
    return rho;
}

// kernel 1: [0,32) rho table · [32,48) nc · [48,8048) time plane
__global__ __launch_bounds__(256) void prep(
    const float* __restrict__ W1, const float* __restrict__ b1,
    const float* __restrict__ W2, const float* __restrict__ b2,
    const float* __restrict__ W3, const float* __restrict__ b3,
    const float* __restrict__ K,
    float* __restrict__ tbl, int* __restrict__ ncArr,
    float* __restrict__ out) {
    if (blockIdx.x < TBLOCKS) {
        __shared__ float sW2[NODES * NODES];
        __shared__ float sW1[NODES], sB1[NODES], sB2[NODES], sW3[NODES];
        __shared__ float sB3;
        for (int i = threadIdx.x; i < NODES * NODES; i += 256) sW2[i] = W2[i];
        if (threadIdx.x < NODES) {
            sW1[threadIdx.x] = W1[threadIdx.x];
            sB1[threadIdx.x] = b1[threadIdx.x];
            sB2[threadIdx.x] = b2[threadIdx.x];
            sW3[threadIdx.x] = W3[threadIdx.x];
        }
        if (threadIdx.x == 0) sB3 = b3[0];
        __syncthreads();
        int idx = blockIdx.x * 256 + threadIdx.x;
        const float h = JMAX / (float)TBL_N;
        tbl[idx] = mlp_rho(h * (float)idx, sW1, sB1, sW2, sB2, sW3, sB3);
    } else if (blockIdx.x < TBLOCKS + NCB) {
        int b = (blockIdx.x - TBLOCKS) * 256 + threadIdx.x;
        float Qmin = 3.3068376f * powf(K[b], 1.3333334f);
        int nc = 1 << 20;
        float Q = 0.0f;
        for (int o = 1; o <= 360; ++o) {
            float BC = 0.1f * (float)o;
            float jc = (0.14f * BC) * 0.125f;
            Q = fmaf(jc, 0.1f, Q);
            if (Q > Qmin) { nc = o; break; }
        }
        ncArr[b] = min(nc, NT - 1);
    } else {
        int e = (blockIdx.x - TBLOCKS - NCB) * 256 + threadIdx.x;  // float4 idx
        int t0 = (e * 4) % NT;                                     // NT % 4 == 0
        float4 v = make_float4(0.1f * (float)t0, 0.1f * (float)(t0 + 1),
                               0.1f * (float)(t0 + 2), 0.1f * (float)(t0 + 3));
        reinterpret_cast<float4*>(out + 3 * (size_t)BATCH * NT)[e] = v;
    }
}

// kernel 2: fused parallel-in-time solve + expansion.
// ONE WAVE per chain (64-thread block, no LDS, no barriers); 4 steps/lane;
// table read directly from global (L2-resident 32 KB).
__global__ __launch_bounds__(64, 4) void fused(
    const float* __restrict__ Cv, const float* __restrict__ jmin,
    const int* __restrict__ ncArr, const float* __restrict__ tbl,
    float* __restrict__ out) {
    const float NI = -3.0e38f;
    const int lane = threadIdx.x;
    const int b = blockIdx.x;
    const float cv = Cv[b];
    const float jm = jmin[b];
    const int   nc = ncArr[b];
    const float k1    = cv * 0.1f;
    const float nk1jm = -k1 * jm;
    const float invh  = (float)TBL_N / JMAX;

    float* __restrict__ oT  = out + (size_t)b * NT;
    float* __restrict__ oR  = out + (size_t)BATCH * NT + (size_t)b * NT;
    float* __restrict__ oC  = out + 2 * (size_t)BATCH * NT + (size_t)b * NT;

    float carry = 50.0f, slope = 0.0f, curv = 0.0f;
    float y = 0.0f;

    for (int c = 0; c < CHUNKS; ++c) {
        const int ob = c << 8;
        const int o0 = ob + 4 * lane, o1 = o0 + 1, o2 = o0 + 2, o3 = o0 + 3;
        const int q = (ob >> 2) + lane;   // float4 index for stores

        if (ob + 255 < nc) {             // closed-form pre-crossing chunk
            float j0 = (o0 == 0) ? 1e-3f : 0.00175f * (float)o0;
            reinterpret_cast<float4*>(oT)[q] = make_float4(0.f, 0.f, 0.f, 0.f);
            reinterpret_cast<float4*>(oR)[q] = make_float4(50.f, 50.f, 50.f, 50.f);
            reinterpret_cast<float4*>(oC)[q] = make_float4(
                j0, 0.00175f * (float)o1, 0.00175f * (float)o2,
                0.00175f * (float)o3);
            continue;
        }

        const float tm0 = 0.1f * (float)o0, tm1 = 0.1f * (float)o1;
        const float tm2 = 0.1f * (float)o2, tm3 = 0.1f * (float)o3;
        const float co0 = 0.14f * tm0, co1 = 0.14f * tm1;
        const float co2 = 0.14f * tm2, co3 = 0.14f * tm3;
        const bool a0 = (o0 >= nc) && (o0 < NT);
        const bool a1 = (o1 >= nc) && (o1 < NT);
        const bool a2 = (o2 >= nc) && (o2 < NT);
        const bool a3 = (o3 >= nc) && (o3 < NT);

        // quadratic warm start (s = 1-based step index within chunk)
        const float s0 = (float)(4 * lane + 1);
        float g0 = fmaf(fmaf(curv, s0, slope), s0, carry);
        const float s1 = s0 + 1.0f;
        float g1 = fmaf(fmaf(curv, s1, slope), s1, carry);
        const float s2 = s0 + 2.0f;
        float g2 = fmaf(fmaf(curv, s2, slope), s2, carry);
        const float s3 = s0 + 3.0f;
        float g3 = fmaf(fmaf(curv, s3, slope), s3, carry);

        float j0, j1, j2, j3, n0, n1, n2, n3;
        for (int it = 0; it < MAXIT; ++it) {
            float rp0 = updpp<0x138, 0xF>(carry, g3);   // wave_shr1, lane0=carry
            float rp1 = g0, rp2 = g1, rp3 = g2;
            j0 = co0 * __builtin_amdgcn_rcpf(fmaf(0.14f, rp0, 1.0f));
            j1 = co1 * __builtin_amdgcn_rcpf(fmaf(0.14f, rp1, 1.0f));
            j2 = co2 * __builtin_amdgcn_rcpf(fmaf(0.14f, rp2, 1.0f));
            j3 = co3 * __builtin_amdgcn_rcpf(fmaf(0.14f, rp3, 1.0f));

            float x0 = fminf(fmaxf(j0 * invh, 0.0f), (float)(TBL_N - 2));
            float x1 = fminf(fmaxf(j1 * invh, 0.0f), (float)(TBL_N - 2));
            float x2 = fminf(fmaxf(j2 * invh, 0.0f), (float)(TBL_N - 2));
            float x3 = fminf(fmaxf(j3 * invh, 0.0f), (float)(TBL_N - 2));
            int ip0 = (int)x0, ip1 = (int)x1, ip2 = (int)x2, ip3 = (int)x3;
            float fr0 = x0 - (float)ip0, fr1 = x1 - (float)ip1;
            float fr2 = x2 - (float)ip2, fr3 = x3 - (float)ip3;
            float ta0 = tbl[ip0], tb0 = tbl[ip0 + 1];
            float ta1 = tbl[ip1], tb1 = tbl[ip1 + 1];
            float ta2 = tbl[ip2], tb2 = tbl[ip2 + 1];
            float ta3 = tbl[ip3], tb3 = tbl[ip3 + 1];
            float rho0 = fmaf(fr0, tb0 - ta0, ta0);
            float rho1 = fmaf(fr1, tb1 - ta1, ta1);
            float rho2 = fmaf(fr2, tb2 - ta2, ta2);
            float rho3 = fmaf(fr3, tb3 - ta3, ta3);

            n0 = fmaf(k1, j0, nk1jm); n1 = fmaf(k1, j1, nk1jm);
            n2 = fmaf(k1, j2, nk1jm); n3 = fmaf(k1, j3, nk1jm);
            float i0 = a0 ? rho0 * n0 : 0.0f;
            float i1 = a1 ? rho1 * n1 : 0.0f;
            float i2 = a2 ? rho2 * n2 : 0.0f;
            float i3 = a3 ? rho3 * n3 : 0.0f;
            float c0 = a0 ? 50.0f : NI, c1 = a1 ? 50.0f : NI;
            float c2 = a2 ? 50.0f : NI, c3 = a3 ? 50.0f : NI;

            float LS0 = i0,        LC0 = c0;
            float LS1 = LS0 + i1,  LC1 = fmaxf(LC0 + i1, c1);
            float LS2 = LS1 + i2,  LC2 = fmaxf(LC1 + i2, c2);
            float LS3 = LS2 + i3,  LC3 = fmaxf(LC2 + i3, c3);

            float Sw = LS3, Cw = LC3;
            scan_sc(Sw, Cw);
            float Se = updpp<0x138, 0xF>(0.0f, Sw);
            float Ce = updpp<0x138, 0xF>(NI, Cw);

            float r0 = fmaxf(carry + (Se + LS0), fmaxf(Ce + LS0, LC0));
            float r1 = fmaxf(carry + (Se + LS1), fmaxf(Ce + LS1, LC1));
            float r2 = fmaxf(carry + (Se + LS2), fmaxf(Ce + LS2, LC2));
            float r3 = fmaxf(carry + (Se + LS3), fmaxf(Ce + LS3, LC3));

            float d = fmaxf(fmaxf(fabsf(r0 - g0), fabsf(r1 - g1)),
                            fmaxf(fabsf(r2 - g2), fabsf(r3 - g3)));
            g0 = r0; g1 = r1; g2 = r2; g3 = r3;
            if (__all(d <= 1.0e-3f)) break;
        }

        // thk clamped-prefix over tinc (limit 0)
        {
            float i0 = a0 ? n0 : 0.0f, i1 = a1 ? n1 : 0.0f;
            float i2 = a2 ? n2 : 0.0f, i3 = a3 ? n3 : 0.0f;
            float c0 = a0 ? 0.0f : NI, c1 = a1 ? 0.0f : NI;
            float c2 = a2 ? 0.0f : NI, c3 = a3 ? 0.0f : NI;
            float LS0 = i0,        LC0 = c0;
            float LS1 = LS0 + i1,  LC1 = fmaxf(LC0 + i1, c1);
            float LS2 = LS1 + i2,  LC2 = fmaxf(LC1 + i2, c2);
            float LS3 = LS2 + i3,  LC3 = fmaxf(LC2 + i3, c3);
            float Sw = LS3, Cw = LC3;
            scan_sc(Sw, Cw);
            float Se = updpp<0x138, 0xF>(0.0f, Sw);
            float Ce = updpp<0x138, 0xF>(NI, Cw);
            float t0 = fmaxf(y + (Se + LS0), fmaxf(Ce + LS0, LC0));
            float t1 = fmaxf(y + (Se + LS1), fmaxf(Ce + LS1, LC1));
            float t2 = fmaxf(y + (Se + LS2), fmaxf(Ce + LS2, LC2));
            float t3 = fmaxf(y + (Se + LS3), fmaxf(Ce + LS3, LC3));

            if (o0 == 0) j0 = 1e-3f;

            if (o3 < NT) {
                reinterpret_cast<float4*>(oT)[q] = make_float4(t0, t1, t2, t3);
                reinterpret_cast<float4*>(oR)[q] = make_float4(g0, g1, g2, g3);
                reinterpret_cast<float4*>(oC)[q] = make_float4(j0, j1, j2, j3);
            }
            y = rdl63(t3);
        }

        float lastR = rdl63(g3);
        float ns = (lastR - carry) * 0.00390625f;
        curv = (ns - slope) * 0.001953125f;
        slope = ns;
        carry = lastR;
    }
}

extern "C" void kernel_launch(void* const* d_in, const int* in_sizes, int n_in,
                              void* d_out, int out_size, void* d_ws, size_t ws_size,
                              hipStream_t stream) {
    const float* Cv   = (const float*)d_in[0];
    const float* K    = (const float*)d_in[1];
    const float* jmin = (const float*)d_in[2];
    const float* W1   = (const float*)d_in[3];
    const float* b1   = (const float*)d_in[4];
    const float* W2   = (const float*)d_in[5];
    const float* b2   = (const float*)d_in[6];
    const float* W3   = (const float*)d_in[7];
    const float* b3   = (const float*)d_in[8];
    float* out = (float*)d_out;
    float* tbl = (float*)d_ws;                                // 32 KB
    int*   ncA = (int*)((char*)d_ws + TBL_N * sizeof(float)); // 16 KB

    prep<<<TBLOCKS + NCB + FILLB, 256, 0, stream>>>(
        W1, b1, W2, b2, W3, b3, K, tbl, ncA, out);
    fused<<<BATCH, 64, 0, stream>>>(Cv, jmin, ncA, tbl, out);
}

// Round 15
// 44.051 us; speedup vs baseline: 5.0283x; 1.6065x over previous
//
#include <hip/hip_runtime.h>

#define NT      2000
#define BATCH   4096
#define NODES   64
#define TBL_N   8192
#define JMAX    3.6f
#define ENTB    (TBL_N / 4)              // 2048 table blocks (4 entries/block, 1 wave each)
#define NCB     (BATCH / 256)            // 16 nc blocks
#define FILLB   (BATCH * NT / 4 / 256)   // 8000 time-plane blocks
#define MAXIT   24
#define CHUNKS  ((NT + 255) / 256)       // 8 chunks of 256 steps (4/lane)

// ---------------- DPP cross-lane helpers (VALU, no DS latency) ----------------
template<int CTRL, int RMASK>
__device__ __forceinline__ float updpp(float oldv, float x) {
    return __int_as_float(__builtin_amdgcn_update_dpp(
        __float_as_int(oldv), __float_as_int(x), CTRL, RMASK, 0xF, false));
}
__device__ __forceinline__ float rdl63(float v) {
    return __int_as_float(__builtin_amdgcn_readlane(__float_as_int(v), 63));
}
__device__ __forceinline__ float rdl(float v, int k) {
    return __int_as_float(__builtin_amdgcn_readlane(__float_as_int(v), k));
}

// inclusive clamped-prefix (S,C) scan over the 64-lane wave.
// compose(left,right): S = Sl+Sr ; C = max(Cl+Sr, Cr).
__device__ __forceinline__ void scan_sc(float& S, float& C) {
    const float NI = -3.0e38f;
    float Su, Cu;
    Su = updpp<0x111, 0xF>(0.0f, S); Cu = updpp<0x111, 0xF>(NI, C);
    C = fmaxf(Cu + S, C); S = Su + S;
    Su = updpp<0x112, 0xF>(0.0f, S); Cu = updpp<0x112, 0xF>(NI, C);
    C = fmaxf(Cu + S, C); S = Su + S;
    Su = updpp<0x114, 0xF>(0.0f, S); Cu = updpp<0x114, 0xF>(NI, C);
    C = fmaxf(Cu + S, C); S = Su + S;
    Su = updpp<0x118, 0xF>(0.0f, S); Cu = updpp<0x118, 0xF>(NI, C);
    C = fmaxf(Cu + S, C); S = Su + S;
    Su = updpp<0x142, 0xA>(0.0f, S); Cu = updpp<0x142, 0xA>(NI, C);
    C = fmaxf(Cu + S, C); S = Su + S;
    Su = updpp<0x143, 0xC>(0.0f, S); Cu = updpp<0x143, 0xC>(NI, C);
    C = fmaxf(Cu + S, C); S = Su + S;
}

// plain inclusive add-scan (for wave reduction)
__device__ __forceinline__ float scan_add(float S) {
    float Su;
    Su = updpp<0x111, 0xF>(0.0f, S); S += Su;
    Su = updpp<0x112, 0xF>(0.0f, S); S += Su;
    Su = updpp<0x114, 0xF>(0.0f, S); S += Su;
    Su = updpp<0x118, 0xF>(0.0f, S); S += Su;
    Su = updpp<0x142, 0xA>(0.0f, S); S += Su;
    Su = updpp<0x143, 0xC>(0.0f, S); S += Su;
    return S;
}

// kernel 1: [0,ENTB) rho table (one wave per entry, cooperative MLP)
//           [ENTB, +NCB) nc per chain · [+FILLB) time plane
__global__ __launch_bounds__(256) void prep(
    const float* __restrict__ W1, const float* __restrict__ b1,
    const float* __restrict__ W2, const float* __restrict__ b2,
    const float* __restrict__ W3, const float* __restrict__ b3,
    const float* __restrict__ K,
    float* __restrict__ tbl, int* __restrict__ ncArr,
    float* __restrict__ out) {
    if (blockIdx.x < ENTB) {
        const int lane = threadIdx.x & 63;
        const int idx = blockIdx.x * 4 + (threadIdx.x >> 6);   // table entry
        const float h = JMAX / (float)TBL_N;
        const float j = h * (float)idx;

        // layer 1: lane t owns hidden unit t
        float h1 = fmaxf(fmaf(j, W1[lane], b1[lane]), 0.0f);

        // layer 2: h2[lane] = relu(b2[lane] + sum_k h1[k] * W2[k*64+lane])
        float acc = b2[lane];
#pragma unroll
        for (int k = 0; k < NODES; ++k) {
            float h1k = rdl(h1, k);                 // SALU broadcast
            acc = fmaf(h1k, W2[k * NODES + lane], acc);   // coalesced load
        }
        float p = fmaxf(acc, 0.0f) * W3[lane];

        // layer 3: rho = sum_lane p + b3
        float rho = rdl63(scan_add(p)) + b3[0];
        if (lane == 0) tbl[idx] = rho;
    } else if (blockIdx.x < ENTB + NCB) {
        int b = (blockIdx.x - ENTB) * 256 + threadIdx.x;
        float Qmin = 3.3068376f * powf(K[b], 1.3333334f);
        int nc = 1 << 20;
        float Q = 0.0f;
        for (int o = 1; o <= 360; ++o) {
            float BC = 0.1f * (float)o;
            float jc = (0.14f * BC) * 0.125f;
            Q = fmaf(jc, 0.1f, Q);
            if (Q > Qmin) { nc = o; break; }
        }
        ncArr[b] = min(nc, NT - 1);
    } else {
        int e = (blockIdx.x - ENTB - NCB) * 256 + threadIdx.x;   // float4 idx
        int t0 = (e * 4) % NT;                                   // NT % 4 == 0
        float4 v = make_float4(0.1f * (float)t0, 0.1f * (float)(t0 + 1),
                               0.1f * (float)(t0 + 2), 0.1f * (float)(t0 + 3));
        reinterpret_cast<float4*>(out + 3 * (size_t)BATCH * NT)[e] = v;
    }
}

// kernel 2: fused parallel-in-time solve + expansion (unchanged from r14).
// ONE WAVE per chain; 4 steps/lane; table read from global (L2-resident 32 KB).
__global__ __launch_bounds__(64, 4) void fused(
    const float* __restrict__ Cv, const float* __restrict__ jmin,
    const int* __restrict__ ncArr, const float* __restrict__ tbl,
    float* __restrict__ out) {
    const float NI = -3.0e38f;
    const int lane = threadIdx.x;
    const int b = blockIdx.x;
    const float cv = Cv[b];
    const float jm = jmin[b];
    const int   nc = ncArr[b];
    const float k1    = cv * 0.1f;
    const float nk1jm = -k1 * jm;
    const float invh  = (float)TBL_N / JMAX;

    float* __restrict__ oT  = out + (size_t)b * NT;
    float* __restrict__ oR  = out + (size_t)BATCH * NT + (size_t)b * NT;
    float* __restrict__ oC  = out + 2 * (size_t)BATCH * NT + (size_t)b * NT;

    float carry = 50.0f, slope = 0.0f, curv = 0.0f;
    float y = 0.0f;

    for (int c = 0; c < CHUNKS; ++c) {
        const int ob = c << 8;
        const int o0 = ob + 4 * lane, o1 = o0 + 1, o2 = o0 + 2, o3 = o0 + 3;
        const int q = (ob >> 2) + lane;

        if (ob + 255 < nc) {             // closed-form pre-crossing chunk
            float j0 = (o0 == 0) ? 1e-3f : 0.00175f * (float)o0;
            reinterpret_cast<float4*>(oT)[q] = make_float4(0.f, 0.f, 0.f, 0.f);
            reinterpret_cast<float4*>(oR)[q] = make_float4(50.f, 50.f, 50.f, 50.f);
            reinterpret_cast<float4*>(oC)[q] = make_float4(
                j0, 0.00175f * (float)o1, 0.00175f * (float)o2,
                0.00175f * (float)o3);
            continue;
        }

        const float tm0 = 0.1f * (float)o0, tm1 = 0.1f * (float)o1;
        const float tm2 = 0.1f * (float)o2, tm3 = 0.1f * (float)o3;
        const float co0 = 0.14f * tm0, co1 = 0.14f * tm1;
        const float co2 = 0.14f * tm2, co3 = 0.14f * tm3;
        const bool a0 = (o0 >= nc) && (o0 < NT);
        const bool a1 = (o1 >= nc) && (o1 < NT);
        const bool a2 = (o2 >= nc) && (o2 < NT);
        const bool a3 = (o3 >= nc) && (o3 < NT);

        const float s0 = (float)(4 * lane + 1);
        float g0 = fmaf(fmaf(curv, s0, slope), s0, carry);
        const float s1 = s0 + 1.0f;
        float g1 = fmaf(fmaf(curv, s1, slope), s1, carry);
        const float s2 = s0 + 2.0f;
        float g2 = fmaf(fmaf(curv, s2, slope), s2, carry);
        const float s3 = s0 + 3.0f;
        float g3 = fmaf(fmaf(curv, s3, slope), s3, carry);

        float j0, j1, j2, j3, n0, n1, n2, n3;
        for (int it = 0; it < MAXIT; ++it) {
            float rp0 = updpp<0x138, 0xF>(carry, g3);   // wave_shr1, lane0=carry
            float rp1 = g0, rp2 = g1, rp3 = g2;
            j0 = co0 * __builtin_amdgcn_rcpf(fmaf(0.14f, rp0, 1.0f));
            j1 = co1 * __builtin_amdgcn_rcpf(fmaf(0.14f, rp1, 1.0f));
            j2 = co2 * __builtin_amdgcn_rcpf(fmaf(0.14f, rp2, 1.0f));
            j3 = co3 * __builtin_amdgcn_rcpf(fmaf(0.14f, rp3, 1.0f));

            float x0 = fminf(fmaxf(j0 * invh, 0.0f), (float)(TBL_N - 2));
            float x1 = fminf(fmaxf(j1 * invh, 0.0f), (float)(TBL_N - 2));
            float x2 = fminf(fmaxf(j2 * invh, 0.0f), (float)(TBL_N - 2));
            float x3 = fminf(fmaxf(j3 * invh, 0.0f), (float)(TBL_N - 2));
            int ip0 = (int)x0, ip1 = (int)x1, ip2 = (int)x2, ip3 = (int)x3;
            float fr0 = x0 - (float)ip0, fr1 = x1 - (float)ip1;
            float fr2 = x2 - (float)ip2, fr3 = x3 - (float)ip3;
            float ta0 = tbl[ip0], tb0 = tbl[ip0 + 1];
            float ta1 = tbl[ip1], tb1 = tbl[ip1 + 1];
            float ta2 = tbl[ip2], tb2 = tbl[ip2 + 1];
            float ta3 = tbl[ip3], tb3 = tbl[ip3 + 1];
            float rho0 = fmaf(fr0, tb0 - ta0, ta0);
            float rho1 = fmaf(fr1, tb1 - ta1, ta1);
            float rho2 = fmaf(fr2, tb2 - ta2, ta2);
            float rho3 = fmaf(fr3, tb3 - ta3, ta3);

            n0 = fmaf(k1, j0, nk1jm); n1 = fmaf(k1, j1, nk1jm);
            n2 = fmaf(k1, j2, nk1jm); n3 = fmaf(k1, j3, nk1jm);
            float i0 = a0 ? rho0 * n0 : 0.0f;
            float i1 = a1 ? rho1 * n1 : 0.0f;
            float i2 = a2 ? rho2 * n2 : 0.0f;
            float i3 = a3 ? rho3 * n3 : 0.0f;
            float c0 = a0 ? 50.0f : NI, c1 = a1 ? 50.0f : NI;
            float c2 = a2 ? 50.0f : NI, c3 = a3 ? 50.0f : NI;

            float LS0 = i0,        LC0 = c0;
            float LS1 = LS0 + i1,  LC1 = fmaxf(LC0 + i1, c1);
            float LS2 = LS1 + i2,  LC2 = fmaxf(LC1 + i2, c2);
            float LS3 = LS2 + i3,  LC3 = fmaxf(LC2 + i3, c3);

            float Sw = LS3, Cw = LC3;
            scan_sc(Sw, Cw);
            float Se = updpp<0x138, 0xF>(0.0f, Sw);
            float Ce = updpp<0x138, 0xF>(NI, Cw);

            float r0 = fmaxf(carry + (Se + LS0), fmaxf(Ce + LS0, LC0));
            float r1 = fmaxf(carry + (Se + LS1), fmaxf(Ce + LS1, LC1));
            float r2 = fmaxf(carry + (Se + LS2), fmaxf(Ce + LS2, LC2));
            float r3 = fmaxf(carry + (Se + LS3), fmaxf(Ce + LS3, LC3));

            float d = fmaxf(fmaxf(fabsf(r0 - g0), fabsf(r1 - g1)),
                            fmaxf(fabsf(r2 - g2), fabsf(r3 - g3)));
            g0 = r0; g1 = r1; g2 = r2; g3 = r3;
            if (__all(d <= 1.0e-3f)) break;
        }

        // thk clamped-prefix over tinc (limit 0)
        {
            float i0 = a0 ? n0 : 0.0f, i1 = a1 ? n1 : 0.0f;
            float i2 = a2 ? n2 : 0.0f, i3 = a3 ? n3 : 0.0f;
            float c0 = a0 ? 0.0f : NI, c1 = a1 ? 0.0f : NI;
            float c2 = a2 ? 0.0f : NI, c3 = a3 ? 0.0f : NI;
            float LS0 = i0,        LC0 = c0;
            float LS1 = LS0 + i1,  LC1 = fmaxf(LC0 + i1, c1);
            float LS2 = LS1 + i2,  LC2 = fmaxf(LC1 + i2, c2);
            float LS3 = LS2 + i3,  LC3 = fmaxf(LC2 + i3, c3);
            float Sw = LS3, Cw = LC3;
            scan_sc(Sw, Cw);
            float Se = updpp<0x138, 0xF>(0.0f, Sw);
            float Ce = updpp<0x138, 0xF>(NI, Cw);
            float t0 = fmaxf(y + (Se + LS0), fmaxf(Ce + LS0, LC0));
            float t1 = fmaxf(y + (Se + LS1), fmaxf(Ce + LS1, LC1));
            float t2 = fmaxf(y + (Se + LS2), fmaxf(Ce + LS2, LC2));
            float t3 = fmaxf(y + (Se + LS3), fmaxf(Ce + LS3, LC3));

            if (o0 == 0) j0 = 1e-3f;

            if (o3 < NT) {
                reinterpret_cast<float4*>(oT)[q] = make_float4(t0, t1, t2, t3);
                reinterpret_cast<float4*>(oR)[q] = make_float4(g0, g1, g2, g3);
                reinterpret_cast<float4*>(oC)[q] = make_float4(j0, j1, j2, j3);
            }
            y = rdl63(t3);
        }

        float lastR = rdl63(g3);
        float ns = (lastR - carry) * 0.00390625f;
        curv = (ns - slope) * 0.001953125f;
        slope = ns;
        carry = lastR;
    }
}

extern "C" void kernel_launch(void* const* d_in, const int* in_sizes, int n_in,
                              void* d_out, int out_size, void* d_ws, size_t ws_size,
                              hipStream_t stream) {
    const float* Cv   = (const float*)d_in[0];
    const float* K    = (const float*)d_in[1];
    const float* jmin = (const float*)d_in[2];
    const float* W1   = (const float*)d_in[3];
    const float* b1   = (const float*)d_in[4];
    const float* W2   = (const float*)d_in[5];
    const float* b2   = (const float*)d_in[6];
    const float* W3   = (const float*)d_in[7];
    const float* b3   = (const float*)d_in[8];
    float* out = (float*)d_out;
    float* tbl = (float*)d_ws;                                // 32 KB
    int*   ncA = (int*)((char*)d_ws + TBL_N * sizeof(float)); // 16 KB

    prep<<<ENTB + NCB + FILLB, 256, 0, stream>>>(
        W1, b1, W2, b2, W3, b3, K, tbl, ncA, out);
    fused<<<BATCH, 64, 0, stream>>>(Cv, jmin, ncA, tbl, out);
}